// Round 1
// baseline (40.391 us; speedup 1.0000x reference)
//
#include <hip/hip_runtime.h>
#include <hip/hip_bf16.h>
#include <stdint.h>

// RelativePositionalEmbedding: out[bh, q, k] = dot(q[bh,q,:], pos_emb[q-k+1023,:]) / 8
// B*H = 32, L = 1024, D = 64, pos_emb rows = 2047. Output (32,1024,1024) fp32.
//
// Per fixed q: OUT_q[m=bh][n=k] = sum_d A[m][d] * Pb[q+1023-n][d]
// -> one 32x1024x64 bf16 MFMA matmul per q, B-operand = contiguous reversed
//    slice of pos_emb (L2-resident, 512 KB total). Write-BW-bound (~128 MB out).

#define LSEQ 1024
#define DDIM 64

typedef __attribute__((ext_vector_type(8))) short bf16x8;
typedef __attribute__((ext_vector_type(16))) float f32x16;

__device__ __forceinline__ unsigned short f2b(float f) {
  union { float f; unsigned u; } c; c.f = f;
  unsigned u = c.u;
  u += 0x7fffu + ((u >> 16) & 1u);   // round-to-nearest-even
  return (unsigned short)(u >> 16);
}

// Convert q (pre-scaled by 1/8, exact pow2) and pos_emb to bf16 in workspace.
// q: 2,097,152 f32 = 524,288 float4; pos_emb: 131,008 f32 = 32,752 float4.
__global__ __launch_bounds__(256) void cvt_kernel(
    const float4* __restrict__ q4, const float4* __restrict__ p4,
    ushort4* __restrict__ qb, ushort4* __restrict__ pb) {
  int i = blockIdx.x * 256 + threadIdx.x;
  if (i < 524288) {
    float4 v = q4[i];
    ushort4 o;
    o.x = f2b(v.x * 0.125f); o.y = f2b(v.y * 0.125f);
    o.z = f2b(v.z * 0.125f); o.w = f2b(v.w * 0.125f);
    qb[i] = o;
  } else {
    int j = i - 524288;
    if (j < 32752) {
      float4 v = p4[j];
      ushort4 o;
      o.x = f2b(v.x); o.y = f2b(v.y); o.z = f2b(v.z); o.w = f2b(v.w);
      pb[j] = o;
    }
  }
}

// One workgroup (4 waves) per q. Wave w owns columns [w*256, w*256+256).
// mfma_f32_32x32x16_bf16: A row = lane&31, k = 8*(lane>>5)+j (j=0..7)
//                         B col = lane&31, k = 8*(lane>>5)+j
//                         D col = lane&31, row = (r&3)+8*(r>>2)+4*(lane>>5)
__global__ __launch_bounds__(256) void rpe_kernel(
    const short* __restrict__ Qb, const short* __restrict__ Pb,
    float* __restrict__ out) {
  const int q    = blockIdx.x;
  const int lane = threadIdx.x & 63;
  const int wave = threadIdx.x >> 6;
  const int l31  = lane & 31;
  const int hi   = lane >> 5;

  // A fragments: Qb[bh = l31][q][16*s + 8*hi + j] — reused for all 8 col-tiles.
  bf16x8 a[4];
  const short* qp = Qb + (l31 * LSEQ + q) * DDIM + hi * 8;
#pragma unroll
  for (int s = 0; s < 4; ++s)
    a[s] = *(const bf16x8*)(qp + 16 * s);

  const int nbase = wave * 256;
#pragma unroll
  for (int t = 0; t < 8; ++t) {
    const int n0 = nbase + 32 * t;
    // B: Pb[row = q + 1023 - (n0 + l31)][16*s + 8*hi + j]
    const short* pp = Pb + (q + 1023 - n0 - l31) * DDIM + hi * 8;
    f32x16 acc;
#pragma unroll
    for (int r = 0; r < 16; ++r) acc[r] = 0.0f;
#pragma unroll
    for (int s = 0; s < 4; ++s) {
      bf16x8 b = *(const bf16x8*)(pp + 16 * s);
      acc = __builtin_amdgcn_mfma_f32_32x32x16_bf16(a[s], b, acc, 0, 0, 0);
    }
    // Store: out[m*L*L + q*L + n], m = (r&3)+8*(r>>2)+4*hi, n = n0+l31.
    // Each store inst: 2 x 128B contiguous segments (fully coalesced).
    float* obase = out + (size_t)hi * 4 * LSEQ * LSEQ + q * LSEQ + n0 + l31;
#pragma unroll
    for (int r = 0; r < 16; ++r) {
      int m = (r & 3) + 8 * (r >> 2);
      obase[(size_t)m * (LSEQ * LSEQ)] = acc[r];
    }
  }
}

extern "C" void kernel_launch(void* const* d_in, const int* in_sizes, int n_in,
                              void* d_out, int out_size, void* d_ws, size_t ws_size,
                              hipStream_t stream) {
  const float* qin = (const float*)d_in[0];
  // d_in[1] (k) unused: only its length (1024) matters, which is fixed.
  const float* pin = (const float*)d_in[2];

  short* qb = (short*)d_ws;                 // 2,097,152 bf16 = 4 MB
  short* pb = (short*)d_ws + 2097152;       // 131,008 bf16 = 262 KB

  cvt_kernel<<<2176, 256, 0, stream>>>((const float4*)qin, (const float4*)pin,
                                       (ushort4*)qb, (ushort4*)pb);
  rpe_kernel<<<1024, 256, 0, stream>>>(qb, pb, (float*)d_out);
}

// Round 2
// 38.437 us; speedup vs baseline: 1.0508x; 1.0508x over previous
//
#include <hip/hip_runtime.h>
#include <hip/hip_bf16.h>
#include <stdint.h>

// RelativePositionalEmbedding: out[bh, q, k] = dot(q[bh,q,:], pos_emb[q-k+1023,:]) / 8
// B*H = 32, L = 1024, D = 64, pos_emb rows = 2047. Output (32,1024,1024) fp32 = 134 MB.
//
// Per fixed q: OUT_q[m=bh][n=k] = sum_d A[m][d] * P[q+1023-n][d]
// -> one 32x1024x64 bf16 MFMA matmul per q. B-operand rows are a contiguous
//    reversed slice of pos_emb -> stage 4KB bands into per-wave-private LDS
//    (global_load_lds w16, XOR-swizzled via pre-swizzled SOURCE address),
//    double-buffered with counted vmcnt (no barriers). Write-BW-bound.

#define LSEQ 1024
#define DDIM 64

typedef __attribute__((ext_vector_type(8))) short bf16x8;
typedef __attribute__((ext_vector_type(16))) float f32x16;

__device__ __forceinline__ unsigned short f2b(float f) {
  union { float f; unsigned u; } c; c.f = f;
  unsigned u = c.u;
  u += 0x7fffu + ((u >> 16) & 1u);   // round-to-nearest-even
  return (unsigned short)(u >> 16);
}

// Convert q (pre-scaled by 1/8, exact pow2) and pos_emb to bf16 in workspace.
// q: 2,097,152 f32 = 524,288 float4; pos_emb: 131,008 f32 = 32,752 float4.
__global__ __launch_bounds__(256) void cvt_kernel(
    const float4* __restrict__ q4, const float4* __restrict__ p4,
    ushort4* __restrict__ qb, ushort4* __restrict__ pb) {
  int i = blockIdx.x * 256 + threadIdx.x;
  if (i < 524288) {
    float4 v = q4[i];
    ushort4 o;
    o.x = f2b(v.x * 0.125f); o.y = f2b(v.y * 0.125f);
    o.z = f2b(v.z * 0.125f); o.w = f2b(v.w * 0.125f);
    qb[i] = o;
  } else {
    int j = i - 524288;
    if (j < 32752) {
      float4 v = p4[j];
      ushort4 o;
      o.x = f2b(v.x); o.y = f2b(v.y); o.z = f2b(v.z); o.w = f2b(v.w);
      pb[j] = o;
    }
  }
}

// One workgroup (4 waves) per q. Wave w owns columns [w*256, w*256+256), 8 tiles.
// mfma_f32_32x32x16_bf16: A row = lane&31, k = 16*s + 8*(lane>>5)+j
//                         B col = lane&31 (-> P row q+1023-n), same k
//                         D col = lane&31, row = (r&3)+8*(r>>2)+4*(lane>>5)
//
// LDS per wave: 2 x 4KB band buffers. Band tile t = P rows [lo, lo+31],
// lo = q + 992 - nbase - 32t (contiguous in P). LDS slot (row r, col16 c)
// holds P[lo+r][c ^ (r&7)] (XOR swizzle, applied on the gload_lds SOURCE
// address since the LDS dest is linear lane*16). Read applies the same XOR.
__global__ __launch_bounds__(256) void rpe_kernel(
    const short* __restrict__ Qb, const short* __restrict__ Pb,
    float* __restrict__ out) {
  __shared__ short lds[4][2][2048];           // [wave][buf][4KB]
  const int q    = blockIdx.x;
  const int tid  = (int)threadIdx.x;
  const int lane = tid & 63;
  const int wave = tid >> 6;
  const int l31  = lane & 31;
  const int hi   = lane >> 5;
  const int nbase = wave << 8;

  // lane-constant swizzled source offset within a 1KB (8-row) sub-block:
  // row-in-block = lane>>3, col16 = (lane&7) ^ (lane>>3)
  const int lane_off = ((lane >> 3) << 7) + ((((lane & 7) ^ (lane >> 3))) << 4);
  const char* Pc = (const char*)Pb;           // row stride 128B

  // ---- prologue: stage tile 0 into buf 0 ----
  {
    const int lo = q + 992 - nbase;
    const char* src = Pc + ((size_t)lo << 7) + lane_off;
#pragma unroll
    for (int j = 0; j < 4; ++j)
      __builtin_amdgcn_global_load_lds(
          (const __attribute__((address_space(1))) void*)(src + (j << 10)),
          (__attribute__((address_space(3))) void*)&lds[wave][0][j << 9],
          16, 0, 0);
  }

  // ---- A fragments: Qb[m = l31][q][16s + 8hi + j], reused for all tiles ----
  bf16x8 a[4];
  const short* qp = Qb + ((l31 << 10) + q) * DDIM + (hi << 3);
#pragma unroll
  for (int s = 0; s < 4; ++s)
    a[s] = *(const bf16x8*)(qp + 16 * s);

  const int rr = 31 - l31;                    // LDS row this lane reads
  const int rx = rr & 7;                      // its XOR key

#pragma unroll
  for (int t = 0; t < 8; ++t) {
    // stage tile t+1 (wraps harmlessly at t=7) into buf (t+1)&1
    {
      const int tn = (t + 1) & 7;
      const int b  = (t + 1) & 1;
      const int lo = q + 992 - nbase - (tn << 5);
      const char* src = Pc + ((size_t)lo << 7) + lane_off;
#pragma unroll
      for (int j = 0; j < 4; ++j)
        __builtin_amdgcn_global_load_lds(
            (const __attribute__((address_space(1))) void*)(src + (j << 10)),
            (__attribute__((address_space(3))) void*)&lds[wave][b][j << 9],
            16, 0, 0);
    }
    // Counted waits (T4): never drain stores.
    // iter 0 outstanding: [stage0(4), Q(4), stage1(4)] -> vmcnt(4) ensures
    //   stage0+Q done. iters>=1: window = 16 stores + 4 stages -> vmcnt(20)
    //   ensures stage(t) done, leaves stores(t-1)+stage(t+1) in flight.
    if (t == 0) asm volatile("s_waitcnt vmcnt(4)" ::: "memory");
    else        asm volatile("s_waitcnt vmcnt(20)" ::: "memory");

    const short* base = &lds[wave][t & 1][rr << 6];
    f32x16 acc;
#pragma unroll
    for (int r = 0; r < 16; ++r) acc[r] = 0.0f;
#pragma unroll
    for (int s = 0; s < 4; ++s) {
      bf16x8 bfr = *(const bf16x8*)(base + (((hi + 2 * s) ^ rx) << 3));
      acc = __builtin_amdgcn_mfma_f32_32x32x16_bf16(a[s], bfr, acc, 0, 0, 0);
    }
    // Store: out[m][q][n0 + l31], m = (r&3)+8*(r>>2)+4*hi.
    // Lanes 0-31 / 32-63 each write one full 128B line per store inst.
    float* obase = out + ((size_t)hi << 22) + (q << 10) + nbase + (t << 5) + l31;
#pragma unroll
    for (int r = 0; r < 16; ++r) {
      const int m = (r & 3) + 8 * (r >> 2);
      obase[(size_t)m << 20] = acc[r];
    }
  }
}

extern "C" void kernel_launch(void* const* d_in, const int* in_sizes, int n_in,
                              void* d_out, int out_size, void* d_ws, size_t ws_size,
                              hipStream_t stream) {
  const float* qin = (const float*)d_in[0];
  // d_in[1] (k) unused: only its length (1024) matters, which is fixed.
  const float* pin = (const float*)d_in[2];

  short* qb = (short*)d_ws;                 // 2,097,152 bf16 = 4 MB
  short* pb = (short*)d_ws + 2097152;       // 131,008 bf16 = 262 KB

  cvt_kernel<<<2176, 256, 0, stream>>>((const float4*)qin, (const float4*)pin,
                                       (ushort4*)qb, (ushort4*)pb);
  rpe_kernel<<<1024, 256, 0, stream>>>(qb, pb, (float*)d_out);
}

// Round 3
// 33.857 us; speedup vs baseline: 1.1930x; 1.1353x over previous
//
#include <hip/hip_runtime.h>
#include <hip/hip_bf16.h>
#include <stdint.h>

// RelativePositionalEmbedding: out[bh, q, k] = dot(q[bh,q,:], pos_emb[q-k+1023,:]) / 8
// B*H = 32, L = 1024, D = 64. Output (32,1024,1024) fp32 = 134 MB -> write-BW-bound.
//
// R2: write-stream locality. (1) XCD-chunked q assignment so each XCD's L2
// eviction window is 32 consecutive q (contiguous 128KB per m-plane);
// (2) NT=2 pair-flush: two adjacent 32-col tiles accumulated, stores paired
// per plane -> 256B contiguous runs. Counted FIFO vmcnt keeps flushes in
// flight (<=36 outstanding, encodable).

#define LSEQ 1024
#define DDIM 64

typedef __attribute__((ext_vector_type(8))) short bf16x8;
typedef __attribute__((ext_vector_type(16))) float f32x16;

__device__ __forceinline__ unsigned short f2b(float f) {
  union { float f; unsigned u; } c; c.f = f;
  unsigned u = c.u;
  u += 0x7fffu + ((u >> 16) & 1u);   // round-to-nearest-even
  return (unsigned short)(u >> 16);
}

// Convert q (pre-scaled by 1/8, exact pow2) and pos_emb to bf16 in workspace.
__global__ __launch_bounds__(256) void cvt_kernel(
    const float4* __restrict__ q4, const float4* __restrict__ p4,
    ushort4* __restrict__ qb, ushort4* __restrict__ pb) {
  int i = blockIdx.x * 256 + threadIdx.x;
  if (i < 524288) {
    float4 v = q4[i];
    ushort4 o;
    o.x = f2b(v.x * 0.125f); o.y = f2b(v.y * 0.125f);
    o.z = f2b(v.z * 0.125f); o.w = f2b(v.w * 0.125f);
    qb[i] = o;
  } else {
    int j = i - 524288;
    if (j < 32752) {
      float4 v = p4[j];
      ushort4 o;
      o.x = f2b(v.x); o.y = f2b(v.y); o.z = f2b(v.z); o.w = f2b(v.w);
      pb[j] = o;
    }
  }
}

// One workgroup (4 waves) per q. Wave w owns columns [w*256, w*256+256), 8 tiles.
// mfma_f32_32x32x16_bf16: A row = lane&31, k = 16*s + 8*(lane>>5)+j
//                         B col = lane&31 (-> P row q+1023-n), same k
//                         D col = lane&31, row = (r&3)+8*(r>>2)+4*(lane>>5)
__global__ __launch_bounds__(256) void rpe_kernel(
    const short* __restrict__ Qb, const short* __restrict__ Pb,
    float* __restrict__ out) {
  __shared__ short lds[4][2][2048];           // [wave][buf][4KB band]
  // XCD-chunked q: XCD x gets q in [x*128, x*128+128) (1024 = 8*128, bijective)
  const int bid  = (int)blockIdx.x;
  const int q    = ((bid & 7) << 7) + (bid >> 3);
  const int tid  = (int)threadIdx.x;
  const int lane = tid & 63;
  const int wave = tid >> 6;
  const int l31  = lane & 31;
  const int hi   = lane >> 5;
  const int nbase = wave << 8;

  // pre-swizzled gload_lds SOURCE offset (rule #21): row-in-8 = lane>>3,
  // col16 = (lane&7) ^ (lane>>3); LDS dest stays linear lane*16.
  const int lane_off = ((lane >> 3) << 7) + ((((lane & 7) ^ (lane >> 3))) << 4);
  const char* Pc = (const char*)Pb;           // P row stride 128B

  auto STAGE = [&](int tt, int buf) {
    const int lo = q + 992 - nbase - (tt << 5);   // band rows [lo, lo+31]
    const char* src = Pc + ((size_t)lo << 7) + lane_off;
#pragma unroll
    for (int j = 0; j < 4; ++j)
      __builtin_amdgcn_global_load_lds(
          (const __attribute__((address_space(1))) void*)(src + (j << 10)),
          (__attribute__((address_space(3))) void*)&lds[wave][buf][j << 9],
          16, 0, 0);
  };

  STAGE(0, 0);                                // s0

  // A fragments: Qb[m = l31][q][16s + 8hi + j], shared by all 8 tiles.
  bf16x8 a[4];
  const short* qp = Qb + ((l31 << 10) + q) * DDIM + (hi << 3);
#pragma unroll
  for (int s = 0; s < 4; ++s)
    a[s] = *(const bf16x8*)(qp + 16 * s);      // A (4 loads)

  STAGE(1, 1);                                // s1

  const int rr = 31 - l31;                    // LDS row this lane reads
  const int rx = rr & 7;                      // its XOR key

  f32x16 accA, accB;
#pragma unroll
  for (int t = 0; t < 8; ++t) {
    // FIFO-derived counted waits (stage(t) must complete; keep flushes live):
    // t: 0->4, 1->4, 2->36, 3->4, 4->36, 5->4, 6->36, 7->0
    if (t == 0 || t == 1 || t == 3 || t == 5)
      asm volatile("s_waitcnt vmcnt(4)" ::: "memory");
    else if (t == 7)
      asm volatile("s_waitcnt vmcnt(0)" ::: "memory");
    else
      asm volatile("s_waitcnt vmcnt(36)" ::: "memory");

    f32x16& acc = (t & 1) ? accB : accA;
#pragma unroll
    for (int r = 0; r < 16; ++r) acc[r] = 0.0f;

    const short* base = &lds[wave][t & 1][rr << 6];
#pragma unroll
    for (int s = 0; s < 4; ++s) {
      bf16x8 bfr = *(const bf16x8*)(base + (((hi + 2 * s) ^ rx) << 3));
      acc = __builtin_amdgcn_mfma_f32_32x32x16_bf16(a[s], bfr, acc, 0, 0, 0);
    }

    if (t & 1) {
      // flush tiles (t-1, t): per plane two adjacent 128B lines = 256B run
      float* ob = out + ((size_t)hi << 22) + (q << 10) + nbase + ((t - 1) << 5) + l31;
#pragma unroll
      for (int r = 0; r < 16; ++r) {
        const int m = (r & 3) + 8 * (r >> 2);
        ob[(size_t)m << 20]      = accA[r];
        ob[((size_t)m << 20) + 32] = accB[r];
      }
    }

    if (t < 6) STAGE(t + 2, t & 1);           // refill the buffer just consumed
  }
}

extern "C" void kernel_launch(void* const* d_in, const int* in_sizes, int n_in,
                              void* d_out, int out_size, void* d_ws, size_t ws_size,
                              hipStream_t stream) {
  const float* qin = (const float*)d_in[0];
  // d_in[1] (k) unused: only its length (1024) matters, which is fixed.
  const float* pin = (const float*)d_in[2];

  short* qb = (short*)d_ws;                 // 2,097,152 bf16 = 4 MB
  short* pb = (short*)d_ws + 2097152;       // 131,008 bf16 = 262 KB

  cvt_kernel<<<2176, 256, 0, stream>>>((const float4*)qin, (const float4*)pin,
                                       (ushort4*)qb, (ushort4*)pb);
  rpe_kernel<<<1024, 256, 0, stream>>>(qb, pb, (float*)d_out);
}